// Round 1
// baseline (407.070 us; speedup 1.0000x reference)
//
#include <hip/hip_runtime.h>

// Problem constants
#define B_TOT 65536
#define WS_P1W 4096                 // permuted bf16 p1W: 48*512*2 = 49152 B
#define WS_EV  (1u << 20)           // per-batch blocks: 512B E + 1024B V = 1536 B * 65536
#define EV_BYTES 100663296u         // 65536 * 1536
#define WS_PART (WS_EV + EV_BYTES)  // per-block D partials: 2048 * 256 * 4 = 2 MB

typedef float f32x4 __attribute__((ext_vector_type(4)));
typedef short s16x8 __attribute__((ext_vector_type(8)));

__device__ __forceinline__ float bf2f(unsigned short h) {
    unsigned u = ((unsigned)h) << 16;
    return __builtin_bit_cast(float, u);
}
// cheap bf16 pair pack: round-half-up (add 0x8000) + v_perm_b32 high-half merge.
__device__ __forceinline__ unsigned pack2(float a, float b) {
    unsigned ua = __builtin_bit_cast(unsigned, a) + 0x8000u;
    unsigned ub = __builtin_bit_cast(unsigned, b) + 0x8000u;
    return __builtin_amdgcn_perm(ub, ua, 0x07060302u);  // lo16=a, hi16=b
}
__device__ __forceinline__ unsigned short f2bf(float f) {
    return (unsigned short)((__builtin_bit_cast(unsigned, f) + 0x8000u) >> 16);
}
__device__ __forceinline__ s16x8 cvt8(float4 a, float4 b) {
    uint4 u;
    u.x = pack2(a.x, a.y); u.y = pack2(a.z, a.w);
    u.z = pack2(b.x, b.y); u.w = pack2(b.z, b.w);
    return __builtin_bit_cast(s16x8, u);
}
#define MFMA(a, b, c) __builtin_amdgcn_mfma_f32_16x16x32_bf16((a), (b), (c), 0, 0, 0)

// ---------------------------------------------------------------------------
// k1: per-batch Q,K,V linears (bf16 MFMA, bias post-added as scalars to save
// VGPRs), normalize Q,K, S = Qn*Kn^T, E=exp(S) -> ws, V -> ws.  Next-batch
// register prefetch hides HBM latency.  D reduction: LDS per-block, then a
// PLAIN coalesced 1KB store of partials (no global atomics -> no same-address
// RMW serialization tail).  __launch_bounds__(256,8) pins VGPR<=64 so all
// 8 blocks/CU (32 waves/CU) stay resident.
// ---------------------------------------------------------------------------
__global__ __launch_bounds__(256, 8) void k1_stats(
    const float* __restrict__ e1, const float* __restrict__ e2,
    const float* __restrict__ qW, const float* __restrict__ qb,
    const float* __restrict__ kW, const float* __restrict__ kb,
    const float* __restrict__ vW, const float* __restrict__ vb,
    char* __restrict__ ws) {

    const int tid = threadIdx.x;
    const int lane = tid & 63;
    const int widx = tid >> 6;
    const int col = lane & 15;      // n-index (e_lo / d) in MFMA layouts
    const int quad = lane >> 4;

    __shared__ __align__(16) unsigned short qk_lds[4][2][16 * 40]; // padded rows (80B)
    __shared__ float Dblk[256];
    Dblk[tid] = 0.f;
    __syncthreads();

    // Weight B-fragments: B_h[k=l][n=e_lo] = W[e_lo+16h][l], lane holds 8 consecutive l.
    s16x8 wq[2], wk[2], wv[2];
    float bq[2], bk[2], bv[2];      // scalar biases (post-added) — saves 18 VGPRs
#pragma unroll
    for (int h = 0; h < 2; ++h) {
        int row = col + 16 * h;
        const float4* pq = (const float4*)(qW + row * 32 + quad * 8);
        const float4* pk = (const float4*)(kW + row * 32 + quad * 8);
        const float4* pv = (const float4*)(vW + row * 32 + quad * 8);
        wq[h] = cvt8(pq[0], pq[1]);
        wk[h] = cvt8(pk[0], pk[1]);
        wv[h] = cvt8(pv[0], pv[1]);
        bq[h] = qb[row]; bk[h] = kb[row]; bv[h] = vb[row];
    }

    unsigned short* qbuf = qk_lds[widx][0];
    unsigned short* kbuf = qk_lds[widx][1];
    float dacc[4] = {0.f, 0.f, 0.f, 0.f};
    char* evbase = ws + WS_EV;
    const f32x4 z = {0.f, 0.f, 0.f, 0.f};

    const int gw = blockIdx.x * 4 + widx;
    const float* p1base = e1 + (size_t)gw * 8 * 512 + col * 32 + quad * 8;
    const float* p2base = e2 + (size_t)gw * 8 * 512 + col * 32 + quad * 8;

    // software-pipelined input loads: issue batch i+1's loads before batch i's compute
    float4 na0 = *(const float4*)(p1base);
    float4 na1 = *(const float4*)(p1base + 4);
    float4 nb0 = *(const float4*)(p2base);
    float4 nb1 = *(const float4*)(p2base + 4);

    for (int i = 0; i < 8; ++i) {
        const int b = gw * 8 + i;
        float4 a0 = na0, a1 = na1, b0 = nb0, b1 = nb1;
        if (i < 7) {
            const float* q1p = p1base + (i + 1) * 512;
            const float* q2p = p2base + (i + 1) * 512;
            na0 = *(const float4*)(q1p);
            na1 = *(const float4*)(q1p + 4);
            nb0 = *(const float4*)(q2p);
            nb1 = *(const float4*)(q2p + 4);
        }
        s16x8 fx1 = cvt8(a0, a1);
        s16x8 fx2 = cvt8(b0, b1);

        f32x4 q1v[2], q2v[2], k1v[2], k2v[2], v1v[2], v2v[2];
#pragma unroll
        for (int h = 0; h < 2; ++h) {
            q1v[h] = MFMA(fx1, wq[h], z); q2v[h] = MFMA(fx2, wq[h], z);
            k1v[h] = MFMA(fx1, wk[h], z); k2v[h] = MFMA(fx2, wk[h], z);
            v1v[h] = MFMA(fx1, wv[h], z); v2v[h] = MFMA(fx2, wv[h], z);
        }
        // bias + product; C/D layout: value (h,r) = M[row=quad*4+r][e=col+16h]
        float Qt[2][4], Kt[2][4], Vv[2][4];
#pragma unroll
        for (int h = 0; h < 2; ++h)
#pragma unroll
            for (int r = 0; r < 4; ++r) {
                Qt[h][r] = (q1v[h][r] + bq[h]) * (q2v[h][r] + bq[h]);
                Kt[h][r] = (k1v[h][r] + bk[h]) * (k2v[h][r] + bk[h]);
                Vv[h][r] = (v1v[h][r] + bv[h]) * (v2v[h][r] + bv[h]);
            }
        // LDS rows store permuted e' = e_lo*2 + h (pairs packable, perm shared by Q,K)
#pragma unroll
        for (int r = 0; r < 4; ++r) {
            int w = (quad * 4 + r) * 20 + col;   // uint index, row stride 20 words
            ((unsigned*)qbuf)[w] = pack2(Qt[0][r], Qt[1][r]);
            ((unsigned*)kbuf)[w] = pack2(Kt[0][r], Kt[1][r]);
        }
        // Read back as A (Q) / B (K) fragments: lane = row col, chunk quad*8
        s16x8 aq = *(const s16x8*)(qbuf + col * 40 + quad * 8);
        s16x8 bk8 = *(const s16x8*)(kbuf + col * 40 + quad * 8);
        float qv[8], kv[8], ssq = 0.f, ssk = 0.f;
#pragma unroll
        for (int j = 0; j < 8; ++j) {
            qv[j] = bf2f((unsigned short)aq[j]); ssq += qv[j] * qv[j];
            kv[j] = bf2f((unsigned short)bk8[j]); ssk += kv[j] * kv[j];
        }
        ssq += __shfl_xor(ssq, 16); ssq += __shfl_xor(ssq, 32);
        ssk += __shfl_xor(ssk, 16); ssk += __shfl_xor(ssk, 32);
        float sq = 1.f / fmaxf(sqrtf(ssq), 1e-12f);
        float sk = 1.f / fmaxf(sqrtf(ssk), 1e-12f);
        uint4 uq, uk;
        uq.x = pack2(qv[0] * sq, qv[1] * sq); uq.y = pack2(qv[2] * sq, qv[3] * sq);
        uq.z = pack2(qv[4] * sq, qv[5] * sq); uq.w = pack2(qv[6] * sq, qv[7] * sq);
        uk.x = pack2(kv[0] * sk, kv[1] * sk); uk.y = pack2(kv[2] * sk, kv[3] * sk);
        uk.z = pack2(kv[4] * sk, kv[5] * sk); uk.w = pack2(kv[6] * sk, kv[7] * sk);
        aq = __builtin_bit_cast(s16x8, uq);
        bk8 = __builtin_bit_cast(s16x8, uk);
        f32x4 S = MFMA(aq, bk8, z);   // S[c=quad*4+r][d=col]

        char* bbase = evbase + (size_t)b * 1536;
        float ex[4];
#pragma unroll
        for (int r = 0; r < 4; ++r) { ex[r] = __expf(S[r]); dacc[r] += ex[r]; }
        // E stored [d][c] bf16: lane covers c = quad*4 .. +3 at row d=col
        uint2 est; est.x = pack2(ex[0], ex[1]); est.y = pack2(ex[2], ex[3]);
        *(uint2*)(bbase + col * 32 + quad * 8) = est;
        // V stored blocked for k2 B-frags: block(h, e_lo=col, c-half quad>>1)
#pragma unroll
        for (int h = 0; h < 2; ++h) {
            uint2 vst;
            vst.x = pack2(Vv[h][0], Vv[h][1]);
            vst.y = pack2(Vv[h][2], Vv[h][3]);
            *(uint2*)(bbase + 512 + ((h * 16 + col) * 2 + (quad >> 1)) * 16 + (quad & 1) * 8) = vst;
        }
    }
    // Denominator: regs -> block LDS (atomics, conflict-free) -> PLAIN coalesced store
#pragma unroll
    for (int r = 0; r < 4; ++r)
        atomicAdd(&Dblk[col * 16 + quad * 4 + r], dacc[r]);
    __syncthreads();
    ((float*)(ws + WS_PART))[blockIdx.x * 256 + tid] = Dblk[tid];
}

// ---------------------------------------------------------------------------
// k1b: (a) blocks 0..95 also build bf16 p1W permuted into k2's i' order (the
// old k0, folded in to save a launch); (b) every block j tree-reduces the 2048
// per-block partials for denominator j and stores 1/D[j] at ws[0..1KB).
// ---------------------------------------------------------------------------
__global__ __launch_bounds__(256) void k1b_prep(const float* __restrict__ p1W,
                                                char* __restrict__ ws) {
    const int t = threadIdx.x;
    const int idx = blockIdx.x * 256 + t;        // 256*256 = 65536
    if (idx < 24576) {                           // 48*512 permute elements
        int jj   = idx & 7;
        int lane = (idx >> 3) & 63;
        int ktnt = idx >> 9;
        int kt = ktnt & 15, nt = ktnt >> 4;
        int n_lo = lane & 15, q8 = lane >> 4;
        int j2  = nt * 16 + n_lo;                // output neuron [0,48)
        int ip  = kt * 32 + q8 * 8 + jj;         // i' in [0,512)
        int e_lo = ip >> 5, qq = (ip >> 3) & 3, hh = (ip >> 2) & 1, r = ip & 3;
        int orig = (qq * 4 + r) * 32 + (e_lo + 16 * hh);
        ((unsigned short*)(ws + WS_P1W))[idx] = f2bf(p1W[j2 * 512 + orig]);
    }
    // Reduce partials[:, j] for j = blockIdx.x, store reciprocal
    const float* part = (const float*)(ws + WS_PART);
    const int j = blockIdx.x;
    float s = 0.f;
#pragma unroll
    for (int k = 0; k < 8; ++k)
        s += part[(size_t)(k * 256 + t) * 256 + j];
    __shared__ float red[256];
    red[t] = s;
    __syncthreads();
    for (int o = 128; o > 0; o >>= 1) {
        if (t < o) red[t] += red[t + o];
        __syncthreads();
    }
    if (t == 0) ((float*)ws)[j] = 1.f / red[0];
}

// ---------------------------------------------------------------------------
// k2: cooperative 4-wave block over ONE 16-batch group.  Phase1 (prefetched
// E/V loads): each wave computes 4 of the 16 per-batch out[d][e] rows into a
// shared 16KB H (bf16, XOR-swizzled chunks).  Phase2 (prefetched weights):
// each wave takes 4 of the 16 k-tiles of MLP1 (MFMA), partial accs reduced
// through LDS (aliased over H).  Phase3: ALL FOUR waves — wave w handles
// r = w (batches quad*4+w) — bias+relu, MLP2, normalize, store.  Tail
// constants hoisted to kernel start; 1/D precomputed by k1b.
// ---------------------------------------------------------------------------
__global__ __launch_bounds__(256) void k2_apply(
    const char* __restrict__ ws, const float* __restrict__ p1b,
    const float* __restrict__ p2W, const float* __restrict__ p2b,
    float* __restrict__ out) {

    const int tid = threadIdx.x;
    const int lane = tid & 63;
    const int widx = tid >> 6;
    const int col = lane & 15;
    const int quad = lane >> 4;
    const int qm = quad & 1;        // mirrored address for upper quads

    __shared__ __align__(16) unsigned short Hs[16 * 512];   // 16 KiB
    float* P = (float*)Hs;          // aliased partial-sum buffer (12 KiB <= 16 KiB)

    // Hoisted tail constants — issued first, latency hidden under phases 1-2
    float p1bias[3], p2w[3][3];
#pragma unroll
    for (int nt = 0; nt < 3; ++nt) {
        p1bias[nt] = p1b[col + 16 * nt];
#pragma unroll
        for (int t2 = 0; t2 < 3; ++t2) p2w[nt][t2] = p2W[t2 * 48 + col + 16 * nt];
    }
    const float pb0 = p2b[0], pb1 = p2b[1], pb2 = p2b[2];

    // 1/denominator (precomputed by k1b), vector-loaded
    const float* Dws = (const float*)ws;
    const float4 dva = *(const float4*)(Dws + col * 16 + qm * 8);
    const float4 dvb = *(const float4*)(Dws + col * 16 + qm * 8 + 4);
    float dinv[8] = {dva.x, dva.y, dva.z, dva.w, dvb.x, dvb.y, dvb.z, dvb.w};

    const char* evbase = ws + WS_EV;
    const unsigned short* p1wp = (const unsigned short*)(ws + WS_P1W);
    const int g = blockIdx.x;
    const f32x4 z = {0.f, 0.f, 0.f, 0.f};
    const s16x8 zz = {0, 0, 0, 0, 0, 0, 0, 0};

    // Phase 1: out[d][e] for batches i = widx*4 .. +3 -> H rows (bf16, swizzled)
    {
        const char* bb0 = evbase + (size_t)(g * 16 + widx * 4) * 1536;
        const int eoff  = col * 32 + qm * 16;
        const int voff0 = 512 + (col * 2 + qm) * 16;
        const int voff1 = 512 + ((16 + col) * 2 + qm) * 16;
        s16x8 ne  = *(const s16x8*)(bb0 + eoff);
        s16x8 nv0 = *(const s16x8*)(bb0 + voff0);
        s16x8 nv1 = *(const s16x8*)(bb0 + voff1);
#pragma unroll
        for (int ii = 0; ii < 4; ++ii) {
            s16x8 eraw = ne, bf0 = nv0, bf1 = nv1;
            if (ii < 3) {
                const char* nb = bb0 + (size_t)(ii + 1) * 1536;
                ne  = *(const s16x8*)(nb + eoff);
                nv0 = *(const s16x8*)(nb + voff0);
                nv1 = *(const s16x8*)(nb + voff1);
            }
            float ef[8];
#pragma unroll
            for (int j = 0; j < 8; ++j)
                ef[j] = bf2f((unsigned short)eraw[j]) * dinv[j];
            uint4 ua;
            ua.x = pack2(ef[0], ef[1]); ua.y = pack2(ef[2], ef[3]);
            ua.z = pack2(ef[4], ef[5]); ua.w = pack2(ef[6], ef[7]);
            s16x8 afrag = __builtin_bit_cast(s16x8, ua);
            if (quad >= 2) { afrag = zz; bf0 = zz; bf1 = zz; }  // K-padding (c>=16 -> 0)
            f32x4 o0 = MFMA(afrag, bf0, z);   // out[d=quad*4+r][e=col]
            f32x4 o1 = MFMA(afrag, bf1, z);   // out[d=quad*4+r][e=col+16]
            uint4 uh;
            uh.x = pack2(o0[0], o0[1]); uh.y = pack2(o0[2], o0[3]);
            uh.z = pack2(o1[0], o1[1]); uh.w = pack2(o1[2], o1[3]);
            const int i = widx * 4 + ii;
            int chunk = (col * 4 + quad) ^ (i & 7);   // 16B-chunk XOR swizzle
            *(uint4*)(Hs + i * 512 + chunk * 8) = uh;
        }
    }
    __syncthreads();

    // Phase 2: MLP1 — H[16 x 512] @ p1Wp^T, wave widx handles kt = widx*4..+3
    f32x4 acc[3] = {z, z, z};
    {
        const int kt0 = widx * 4;
        s16x8 nw0 = *(const s16x8*)(p1wp + ((0 * 16 + kt0) * 64 + lane) * 8);
        s16x8 nw1 = *(const s16x8*)(p1wp + ((1 * 16 + kt0) * 64 + lane) * 8);
        s16x8 nw2 = *(const s16x8*)(p1wp + ((2 * 16 + kt0) * 64 + lane) * 8);
#pragma unroll
        for (int t2 = 0; t2 < 4; ++t2) {
            const int kt = widx * 4 + t2;
            s16x8 w0 = nw0, w1 = nw1, w2 = nw2;
            if (t2 < 3) {
                nw0 = *(const s16x8*)(p1wp + ((0 * 16 + kt + 1) * 64 + lane) * 8);
                nw1 = *(const s16x8*)(p1wp + ((1 * 16 + kt + 1) * 64 + lane) * 8);
                nw2 = *(const s16x8*)(p1wp + ((2 * 16 + kt + 1) * 64 + lane) * 8);
            }
            int chunk = (kt * 4 + quad) ^ (col & 7);
            s16x8 a = *(const s16x8*)(Hs + col * 512 + chunk * 8);
            acc[0] = MFMA(a, w0, acc[0]);
            acc[1] = MFMA(a, w1, acc[1]);
            acc[2] = MFMA(a, w2, acc[2]);
        }
    }
    __syncthreads();   // H reads done before P overwrites it

    // partials -> LDS: P[widx][lane][nt*4+r], lane stride 12 floats (48B)
#pragma unroll
    for (int nt = 0; nt < 3; ++nt)
        *(f32x4*)(P + (widx * 64 + lane) * 12 + nt * 4) = acc[nt];
    __syncthreads();

    // Phase 3: all 4 waves — wave widx handles r = widx (batches quad*4+widx)
    {
        float s3[3] = {0.f, 0.f, 0.f};
#pragma unroll
        for (int w = 0; w < 4; ++w)
#pragma unroll
            for (int nt = 0; nt < 3; ++nt)
                s3[nt] += P[(w * 64 + lane) * 12 + nt * 4 + widx];
        float pp[3] = {0.f, 0.f, 0.f};
#pragma unroll
        for (int nt = 0; nt < 3; ++nt) {
            float hv = fmaxf(s3[nt] + p1bias[nt], 0.f);
            pp[0] += hv * p2w[nt][0];
            pp[1] += hv * p2w[nt][1];
            pp[2] += hv * p2w[nt][2];
        }
#pragma unroll
        for (int m = 1; m <= 8; m <<= 1) {
            pp[0] += __shfl_xor(pp[0], m);
            pp[1] += __shfl_xor(pp[1], m);
            pp[2] += __shfl_xor(pp[2], m);
        }
        float h0 = pp[0] + pb0, h1 = pp[1] + pb1, h2 = pp[2] + pb2;
        float inv = 1.f / fmaxf(sqrtf(h0 * h0 + h1 * h1 + h2 * h2), 1e-12f);
        if (col < 3) {
            float v = (col == 0) ? h0 : ((col == 1) ? h1 : h2);
            out[(size_t)(g * 16 + quad * 4 + widx) * 3 + col] = v * inv;
        }
    }
}

// ---------------------------------------------------------------------------
extern "C" void kernel_launch(void* const* d_in, const int* in_sizes, int n_in,
                              void* d_out, int out_size, void* d_ws, size_t ws_size,
                              hipStream_t stream) {
    const float* e1  = (const float*)d_in[0];
    const float* e2  = (const float*)d_in[1];
    const float* qW  = (const float*)d_in[2];
    const float* qb  = (const float*)d_in[3];
    const float* kW  = (const float*)d_in[4];
    const float* kb  = (const float*)d_in[5];
    const float* vW  = (const float*)d_in[6];
    const float* vb  = (const float*)d_in[7];
    const float* p1W = (const float*)d_in[8];
    const float* p1b = (const float*)d_in[9];
    const float* p2W = (const float*)d_in[10];
    const float* p2b = (const float*)d_in[11];
    float* out = (float*)d_out;
    char* ws = (char*)d_ws;

    k1_stats<<<2048, 256, 0, stream>>>(e1, e2, qW, qb, kW, kb, vW, vb, ws);
    k1b_prep<<<256, 256, 0, stream>>>(p1W, ws);
    k2_apply<<<4096, 256, 0, stream>>>(ws, p1b, p2W, p2b, out);
}

// Round 2
// 341.395 us; speedup vs baseline: 1.1924x; 1.1924x over previous
//
#include <hip/hip_runtime.h>

// Problem constants
#define B_TOT 65536
#define WS_P1W 4096                 // permuted bf16 p1W: 48*512*2 = 49152 B
#define WS_EV  (1u << 20)           // per-batch blocks: 512B E + 1024B V = 1536 B * 65536
#define EV_BYTES 100663296u         // 65536 * 1536
#define WS_PART (WS_EV + EV_BYTES)  // per-block D partials: 2048 * 256 * 4 = 2 MB

typedef float f32x4 __attribute__((ext_vector_type(4)));
typedef short s16x8 __attribute__((ext_vector_type(8)));

__device__ __forceinline__ float bf2f(unsigned short h) {
    unsigned u = ((unsigned)h) << 16;
    return __builtin_bit_cast(float, u);
}
// cheap bf16 pair pack: round-half-up (add 0x8000) + v_perm_b32 high-half merge.
__device__ __forceinline__ unsigned pack2(float a, float b) {
    unsigned ua = __builtin_bit_cast(unsigned, a) + 0x8000u;
    unsigned ub = __builtin_bit_cast(unsigned, b) + 0x8000u;
    return __builtin_amdgcn_perm(ub, ua, 0x07060302u);  // lo16=a, hi16=b
}
__device__ __forceinline__ unsigned short f2bf(float f) {
    return (unsigned short)((__builtin_bit_cast(unsigned, f) + 0x8000u) >> 16);
}
__device__ __forceinline__ s16x8 cvt8(float4 a, float4 b) {
    uint4 u;
    u.x = pack2(a.x, a.y); u.y = pack2(a.z, a.w);
    u.z = pack2(b.x, b.y); u.w = pack2(b.z, b.w);
    return __builtin_bit_cast(s16x8, u);
}
#define MFMA(a, b, c) __builtin_amdgcn_mfma_f32_16x16x32_bf16((a), (b), (c), 0, 0, 0)

// ---------------------------------------------------------------------------
// k1: per-batch Q,K,V linears (bf16 MFMA, bias post-added as scalars),
// normalize Q,K, S = Qn*Kn^T, E=exp(S) -> ws, V -> ws.  Next-batch register
// prefetch hides HBM latency.  D reduction: LDS per-block, then a PLAIN
// coalesced 1KB store of partials (no global atomics -> no same-address RMW
// serialization tail).  NO min-waves pin: R1 showed __launch_bounds__(256,8)
// forces VGPR=32 -> scratch spills (+330 MB HBM traffic, k1 127->181 us).
// At ~96 VGPR we still get 5 waves/SIMD = 20 waves/CU, spill-free.
// ---------------------------------------------------------------------------
__global__ __launch_bounds__(256) void k1_stats(
    const float* __restrict__ e1, const float* __restrict__ e2,
    const float* __restrict__ qW, const float* __restrict__ qb,
    const float* __restrict__ kW, const float* __restrict__ kb,
    const float* __restrict__ vW, const float* __restrict__ vb,
    char* __restrict__ ws) {

    const int tid = threadIdx.x;
    const int lane = tid & 63;
    const int widx = tid >> 6;
    const int col = lane & 15;      // n-index (e_lo / d) in MFMA layouts
    const int quad = lane >> 4;

    __shared__ __align__(16) unsigned short qk_lds[4][2][16 * 40]; // padded rows (80B)
    __shared__ float Dblk[256];
    Dblk[tid] = 0.f;
    __syncthreads();

    // Weight B-fragments: B_h[k=l][n=e_lo] = W[e_lo+16h][l], lane holds 8 consecutive l.
    s16x8 wq[2], wk[2], wv[2];
    float bq[2], bk[2], bv[2];      // scalar biases (post-added)
#pragma unroll
    for (int h = 0; h < 2; ++h) {
        int row = col + 16 * h;
        const float4* pq = (const float4*)(qW + row * 32 + quad * 8);
        const float4* pk = (const float4*)(kW + row * 32 + quad * 8);
        const float4* pv = (const float4*)(vW + row * 32 + quad * 8);
        wq[h] = cvt8(pq[0], pq[1]);
        wk[h] = cvt8(pk[0], pk[1]);
        wv[h] = cvt8(pv[0], pv[1]);
        bq[h] = qb[row]; bk[h] = kb[row]; bv[h] = vb[row];
    }

    unsigned short* qbuf = qk_lds[widx][0];
    unsigned short* kbuf = qk_lds[widx][1];
    float dacc[4] = {0.f, 0.f, 0.f, 0.f};
    char* evbase = ws + WS_EV;
    const f32x4 z = {0.f, 0.f, 0.f, 0.f};

    const int gw = blockIdx.x * 4 + widx;
    const float* p1base = e1 + (size_t)gw * 8 * 512 + col * 32 + quad * 8;
    const float* p2base = e2 + (size_t)gw * 8 * 512 + col * 32 + quad * 8;

    // software-pipelined input loads: issue batch i+1's loads before batch i's compute
    float4 na0 = *(const float4*)(p1base);
    float4 na1 = *(const float4*)(p1base + 4);
    float4 nb0 = *(const float4*)(p2base);
    float4 nb1 = *(const float4*)(p2base + 4);

    for (int i = 0; i < 8; ++i) {
        const int b = gw * 8 + i;
        float4 a0 = na0, a1 = na1, b0 = nb0, b1 = nb1;
        if (i < 7) {
            const float* q1p = p1base + (i + 1) * 512;
            const float* q2p = p2base + (i + 1) * 512;
            na0 = *(const float4*)(q1p);
            na1 = *(const float4*)(q1p + 4);
            nb0 = *(const float4*)(q2p);
            nb1 = *(const float4*)(q2p + 4);
        }
        s16x8 fx1 = cvt8(a0, a1);
        s16x8 fx2 = cvt8(b0, b1);

        f32x4 q1v[2], q2v[2], k1v[2], k2v[2], v1v[2], v2v[2];
#pragma unroll
        for (int h = 0; h < 2; ++h) {
            q1v[h] = MFMA(fx1, wq[h], z); q2v[h] = MFMA(fx2, wq[h], z);
            k1v[h] = MFMA(fx1, wk[h], z); k2v[h] = MFMA(fx2, wk[h], z);
            v1v[h] = MFMA(fx1, wv[h], z); v2v[h] = MFMA(fx2, wv[h], z);
        }
        // bias + product; C/D layout: value (h,r) = M[row=quad*4+r][e=col+16h]
        float Qt[2][4], Kt[2][4], Vv[2][4];
#pragma unroll
        for (int h = 0; h < 2; ++h)
#pragma unroll
            for (int r = 0; r < 4; ++r) {
                Qt[h][r] = (q1v[h][r] + bq[h]) * (q2v[h][r] + bq[h]);
                Kt[h][r] = (k1v[h][r] + bk[h]) * (k2v[h][r] + bk[h]);
                Vv[h][r] = (v1v[h][r] + bv[h]) * (v2v[h][r] + bv[h]);
            }
        // LDS rows store permuted e' = e_lo*2 + h (pairs packable, perm shared by Q,K)
#pragma unroll
        for (int r = 0; r < 4; ++r) {
            int w = (quad * 4 + r) * 20 + col;   // uint index, row stride 20 words
            ((unsigned*)qbuf)[w] = pack2(Qt[0][r], Qt[1][r]);
            ((unsigned*)kbuf)[w] = pack2(Kt[0][r], Kt[1][r]);
        }
        // Read back as A (Q) / B (K) fragments: lane = row col, chunk quad*8
        s16x8 aq = *(const s16x8*)(qbuf + col * 40 + quad * 8);
        s16x8 bk8 = *(const s16x8*)(kbuf + col * 40 + quad * 8);
        float qv[8], kv[8], ssq = 0.f, ssk = 0.f;
#pragma unroll
        for (int j = 0; j < 8; ++j) {
            qv[j] = bf2f((unsigned short)aq[j]); ssq += qv[j] * qv[j];
            kv[j] = bf2f((unsigned short)bk8[j]); ssk += kv[j] * kv[j];
        }
        ssq += __shfl_xor(ssq, 16); ssq += __shfl_xor(ssq, 32);
        ssk += __shfl_xor(ssk, 16); ssk += __shfl_xor(ssk, 32);
        float sq = 1.f / fmaxf(sqrtf(ssq), 1e-12f);
        float sk = 1.f / fmaxf(sqrtf(ssk), 1e-12f);
        uint4 uq, uk;
        uq.x = pack2(qv[0] * sq, qv[1] * sq); uq.y = pack2(qv[2] * sq, qv[3] * sq);
        uq.z = pack2(qv[4] * sq, qv[5] * sq); uq.w = pack2(qv[6] * sq, qv[7] * sq);
        uk.x = pack2(kv[0] * sk, kv[1] * sk); uk.y = pack2(kv[2] * sk, kv[3] * sk);
        uk.z = pack2(kv[4] * sk, kv[5] * sk); uk.w = pack2(kv[6] * sk, kv[7] * sk);
        aq = __builtin_bit_cast(s16x8, uq);
        bk8 = __builtin_bit_cast(s16x8, uk);
        f32x4 S = MFMA(aq, bk8, z);   // S[c=quad*4+r][d=col]

        char* bbase = evbase + (size_t)b * 1536;
        float ex[4];
#pragma unroll
        for (int r = 0; r < 4; ++r) { ex[r] = __expf(S[r]); dacc[r] += ex[r]; }
        // E stored [d][c] bf16: lane covers c = quad*4 .. +3 at row d=col
        uint2 est; est.x = pack2(ex[0], ex[1]); est.y = pack2(ex[2], ex[3]);
        *(uint2*)(bbase + col * 32 + quad * 8) = est;
        // V stored blocked for k2 B-frags: block(h, e_lo=col, c-half quad>>1)
#pragma unroll
        for (int h = 0; h < 2; ++h) {
            uint2 vst;
            vst.x = pack2(Vv[h][0], Vv[h][1]);
            vst.y = pack2(Vv[h][2], Vv[h][3]);
            *(uint2*)(bbase + 512 + ((h * 16 + col) * 2 + (quad >> 1)) * 16 + (quad & 1) * 8) = vst;
        }
    }
    // Denominator: regs -> block LDS (atomics, conflict-free) -> PLAIN coalesced store
#pragma unroll
    for (int r = 0; r < 4; ++r)
        atomicAdd(&Dblk[col * 16 + quad * 4 + r], dacc[r]);
    __syncthreads();
    ((float*)(ws + WS_PART))[blockIdx.x * 256 + tid] = Dblk[tid];
}

// ---------------------------------------------------------------------------
// k1b: (a) blocks 0..95 also build bf16 p1W permuted into k2's i' order;
// (b) every block j tree-reduces the 2048 per-block partials for denominator
// j and stores 1/D[j] at ws[0..1KB).
// ---------------------------------------------------------------------------
__global__ __launch_bounds__(256) void k1b_prep(const float* __restrict__ p1W,
                                                char* __restrict__ ws) {
    const int t = threadIdx.x;
    const int idx = blockIdx.x * 256 + t;        // 256*256 = 65536
    if (idx < 24576) {                           // 48*512 permute elements
        int jj   = idx & 7;
        int lane = (idx >> 3) & 63;
        int ktnt = idx >> 9;
        int kt = ktnt & 15, nt = ktnt >> 4;
        int n_lo = lane & 15, q8 = lane >> 4;
        int j2  = nt * 16 + n_lo;                // output neuron [0,48)
        int ip  = kt * 32 + q8 * 8 + jj;         // i' in [0,512)
        int e_lo = ip >> 5, qq = (ip >> 3) & 3, hh = (ip >> 2) & 1, r = ip & 3;
        int orig = (qq * 4 + r) * 32 + (e_lo + 16 * hh);
        ((unsigned short*)(ws + WS_P1W))[idx] = f2bf(p1W[j2 * 512 + orig]);
    }
    // Reduce partials[:, j] for j = blockIdx.x, store reciprocal
    const float* part = (const float*)(ws + WS_PART);
    const int j = blockIdx.x;
    float s = 0.f;
#pragma unroll
    for (int k = 0; k < 8; ++k)
        s += part[(size_t)(k * 256 + t) * 256 + j];
    __shared__ float red[256];
    red[t] = s;
    __syncthreads();
    for (int o = 128; o > 0; o >>= 1) {
        if (t < o) red[t] += red[t + o];
        __syncthreads();
    }
    if (t == 0) ((float*)ws)[j] = 1.f / red[0];
}

// ---------------------------------------------------------------------------
// k2: cooperative 4-wave block over ONE 16-batch group.  Phase1 (prefetched
// E/V loads): each wave computes 4 of the 16 per-batch out[d][e] rows into a
// shared 16KB H (bf16, XOR-swizzled chunks).  Phase2 (prefetched weights):
// each wave takes 4 of the 16 k-tiles of MLP1 (MFMA), partial accs reduced
// through LDS (aliased over H).  Phase3: ALL FOUR waves — wave w handles
// r = w — bias+relu, MLP2, normalize, store.  Tail constants hoisted; 1/D
// precomputed by k1b.
// ---------------------------------------------------------------------------
__global__ __launch_bounds__(256) void k2_apply(
    const char* __restrict__ ws, const float* __restrict__ p1b,
    const float* __restrict__ p2W, const float* __restrict__ p2b,
    float* __restrict__ out) {

    const int tid = threadIdx.x;
    const int lane = tid & 63;
    const int widx = tid >> 6;
    const int col = lane & 15;
    const int quad = lane >> 4;
    const int qm = quad & 1;        // mirrored address for upper quads

    __shared__ __align__(16) unsigned short Hs[16 * 512];   // 16 KiB
    float* P = (float*)Hs;          // aliased partial-sum buffer (12 KiB <= 16 KiB)

    // Hoisted tail constants — issued first, latency hidden under phases 1-2
    float p1bias[3], p2w[3][3];
#pragma unroll
    for (int nt = 0; nt < 3; ++nt) {
        p1bias[nt] = p1b[col + 16 * nt];
#pragma unroll
        for (int t2 = 0; t2 < 3; ++t2) p2w[nt][t2] = p2W[t2 * 48 + col + 16 * nt];
    }
    const float pb0 = p2b[0], pb1 = p2b[1], pb2 = p2b[2];

    // 1/denominator (precomputed by k1b), vector-loaded
    const float* Dws = (const float*)ws;
    const float4 dva = *(const float4*)(Dws + col * 16 + qm * 8);
    const float4 dvb = *(const float4*)(Dws + col * 16 + qm * 8 + 4);
    float dinv[8] = {dva.x, dva.y, dva.z, dva.w, dvb.x, dvb.y, dvb.z, dvb.w};

    const char* evbase = ws + WS_EV;
    const unsigned short* p1wp = (const unsigned short*)(ws + WS_P1W);
    const int g = blockIdx.x;
    const f32x4 z = {0.f, 0.f, 0.f, 0.f};
    const s16x8 zz = {0, 0, 0, 0, 0, 0, 0, 0};

    // Phase 1: out[d][e] for batches i = widx*4 .. +3 -> H rows (bf16, swizzled)
    {
        const char* bb0 = evbase + (size_t)(g * 16 + widx * 4) * 1536;
        const int eoff  = col * 32 + qm * 16;
        const int voff0 = 512 + (col * 2 + qm) * 16;
        const int voff1 = 512 + ((16 + col) * 2 + qm) * 16;
        s16x8 ne  = *(const s16x8*)(bb0 + eoff);
        s16x8 nv0 = *(const s16x8*)(bb0 + voff0);
        s16x8 nv1 = *(const s16x8*)(bb0 + voff1);
#pragma unroll
        for (int ii = 0; ii < 4; ++ii) {
            s16x8 eraw = ne, bf0 = nv0, bf1 = nv1;
            if (ii < 3) {
                const char* nb = bb0 + (size_t)(ii + 1) * 1536;
                ne  = *(const s16x8*)(nb + eoff);
                nv0 = *(const s16x8*)(nb + voff0);
                nv1 = *(const s16x8*)(nb + voff1);
            }
            float ef[8];
#pragma unroll
            for (int j = 0; j < 8; ++j)
                ef[j] = bf2f((unsigned short)eraw[j]) * dinv[j];
            uint4 ua;
            ua.x = pack2(ef[0], ef[1]); ua.y = pack2(ef[2], ef[3]);
            ua.z = pack2(ef[4], ef[5]); ua.w = pack2(ef[6], ef[7]);
            s16x8 afrag = __builtin_bit_cast(s16x8, ua);
            if (quad >= 2) { afrag = zz; bf0 = zz; bf1 = zz; }  // K-padding (c>=16 -> 0)
            f32x4 o0 = MFMA(afrag, bf0, z);   // out[d=quad*4+r][e=col]
            f32x4 o1 = MFMA(afrag, bf1, z);   // out[d=quad*4+r][e=col+16]
            uint4 uh;
            uh.x = pack2(o0[0], o0[1]); uh.y = pack2(o0[2], o0[3]);
            uh.z = pack2(o1[0], o1[1]); uh.w = pack2(o1[2], o1[3]);
            const int i = widx * 4 + ii;
            int chunk = (col * 4 + quad) ^ (i & 7);   // 16B-chunk XOR swizzle
            *(uint4*)(Hs + i * 512 + chunk * 8) = uh;
        }
    }
    __syncthreads();

    // Phase 2: MLP1 — H[16 x 512] @ p1Wp^T, wave widx handles kt = widx*4..+3
    f32x4 acc[3] = {z, z, z};
    {
        const int kt0 = widx * 4;
        s16x8 nw0 = *(const s16x8*)(p1wp + ((0 * 16 + kt0) * 64 + lane) * 8);
        s16x8 nw1 = *(const s16x8*)(p1wp + ((1 * 16 + kt0) * 64 + lane) * 8);
        s16x8 nw2 = *(const s16x8*)(p1wp + ((2 * 16 + kt0) * 64 + lane) * 8);
#pragma unroll
        for (int t2 = 0; t2 < 4; ++t2) {
            const int kt = widx * 4 + t2;
            s16x8 w0 = nw0, w1 = nw1, w2 = nw2;
            if (t2 < 3) {
                nw0 = *(const s16x8*)(p1wp + ((0 * 16 + kt + 1) * 64 + lane) * 8);
                nw1 = *(const s16x8*)(p1wp + ((1 * 16 + kt + 1) * 64 + lane) * 8);
                nw2 = *(const s16x8*)(p1wp + ((2 * 16 + kt + 1) * 64 + lane) * 8);
            }
            int chunk = (kt * 4 + quad) ^ (col & 7);
            s16x8 a = *(const s16x8*)(Hs + col * 512 + chunk * 8);
            acc[0] = MFMA(a, w0, acc[0]);
            acc[1] = MFMA(a, w1, acc[1]);
            acc[2] = MFMA(a, w2, acc[2]);
        }
    }
    __syncthreads();   // H reads done before P overwrites it

    // partials -> LDS: P[widx][lane][nt*4+r], lane stride 12 floats (48B)
#pragma unroll
    for (int nt = 0; nt < 3; ++nt)
        *(f32x4*)(P + (widx * 64 + lane) * 12 + nt * 4) = acc[nt];
    __syncthreads();

    // Phase 3: all 4 waves — wave widx handles r = widx (batches quad*4+widx)
    {
        float s3[3] = {0.f, 0.f, 0.f};
#pragma unroll
        for (int w = 0; w < 4; ++w)
#pragma unroll
            for (int nt = 0; nt < 3; ++nt)
                s3[nt] += P[(w * 64 + lane) * 12 + nt * 4 + widx];
        float pp[3] = {0.f, 0.f, 0.f};
#pragma unroll
        for (int nt = 0; nt < 3; ++nt) {
            float hv = fmaxf(s3[nt] + p1bias[nt], 0.f);
            pp[0] += hv * p2w[nt][0];
            pp[1] += hv * p2w[nt][1];
            pp[2] += hv * p2w[nt][2];
        }
#pragma unroll
        for (int m = 1; m <= 8; m <<= 1) {
            pp[0] += __shfl_xor(pp[0], m);
            pp[1] += __shfl_xor(pp[1], m);
            pp[2] += __shfl_xor(pp[2], m);
        }
        float h0 = pp[0] + pb0, h1 = pp[1] + pb1, h2 = pp[2] + pb2;
        float inv = 1.f / fmaxf(sqrtf(h0 * h0 + h1 * h1 + h2 * h2), 1e-12f);
        if (col < 3) {
            float v = (col == 0) ? h0 : ((col == 1) ? h1 : h2);
            out[(size_t)(g * 16 + quad * 4 + widx) * 3 + col] = v * inv;
        }
    }
}

// ---------------------------------------------------------------------------
extern "C" void kernel_launch(void* const* d_in, const int* in_sizes, int n_in,
                              void* d_out, int out_size, void* d_ws, size_t ws_size,
                              hipStream_t stream) {
    const float* e1  = (const float*)d_in[0];
    const float* e2  = (const float*)d_in[1];
    const float* qW  = (const float*)d_in[2];
    const float* qb  = (const float*)d_in[3];
    const float* kW  = (const float*)d_in[4];
    const float* kb  = (const float*)d_in[5];
    const float* vW  = (const float*)d_in[6];
    const float* vb  = (const float*)d_in[7];
    const float* p1W = (const float*)d_in[8];
    const float* p1b = (const float*)d_in[9];
    const float* p2W = (const float*)d_in[10];
    const float* p2b = (const float*)d_in[11];
    float* out = (float*)d_out;
    char* ws = (char*)d_ws;

    k1_stats<<<2048, 256, 0, stream>>>(e1, e2, qW, qb, kW, kb, vW, vb, ws);
    k1b_prep<<<256, 256, 0, stream>>>(p1W, ws);
    k2_apply<<<4096, 256, 0, stream>>>(ws, p1b, p2W, p2b, out);
}

// Round 3
// 337.016 us; speedup vs baseline: 1.2079x; 1.0130x over previous
//
#include <hip/hip_runtime.h>

// Problem constants
#define B_TOT 65536
#define WS_P1W 4096                 // permuted bf16 p1W: 48*512*2 = 49152 B
#define WS_EV  (1u << 20)           // per-batch blocks: 512B E + 1024B V = 1536 B * 65536
#define EV_BYTES 100663296u         // 65536 * 1536
#define WS_PART (WS_EV + EV_BYTES)  // per-block D partials: 2048 * 256 * 4 = 2 MB

typedef float f32x4 __attribute__((ext_vector_type(4)));
typedef short s16x8 __attribute__((ext_vector_type(8)));

__device__ __forceinline__ float bf2f(unsigned short h) {
    unsigned u = ((unsigned)h) << 16;
    return __builtin_bit_cast(float, u);
}
// cheap bf16 pair pack: round-half-up (add 0x8000) + v_perm_b32 high-half merge.
__device__ __forceinline__ unsigned pack2(float a, float b) {
    unsigned ua = __builtin_bit_cast(unsigned, a) + 0x8000u;
    unsigned ub = __builtin_bit_cast(unsigned, b) + 0x8000u;
    return __builtin_amdgcn_perm(ub, ua, 0x07060302u);  // lo16=a, hi16=b
}
__device__ __forceinline__ unsigned short f2bf(float f) {
    return (unsigned short)((__builtin_bit_cast(unsigned, f) + 0x8000u) >> 16);
}
__device__ __forceinline__ s16x8 cvt8(float4 a, float4 b) {
    uint4 u;
    u.x = pack2(a.x, a.y); u.y = pack2(a.z, a.w);
    u.z = pack2(b.x, b.y); u.w = pack2(b.z, b.w);
    return __builtin_bit_cast(s16x8, u);
}
#define MFMA(a, b, c) __builtin_amdgcn_mfma_f32_16x16x32_bf16((a), (b), (c), 0, 0, 0)

// ---------------------------------------------------------------------------
// k1: per-batch Q,K,V linears (bf16 MFMA, bias folded into accumulator —
// R0-proven, 1 mul/elem product).  DEFERRED NORMALIZATION: S = MFMA on RAW
// bf16 Q,K fragments issues immediately after the LDS transpose read-back;
// row/col inverse norms are computed in parallel and applied to S afterward
// (Qn·Kn == (Q·K)/(||Q|| ||K||)).  This removes the renormalize+repack
// (~50 VALU) from the serial chain.  invk is lane-local (col=d); invq needs
// 4 dynamic shuffles (row-indexed).  E=exp(S)->ws, V->ws.  D reduction: LDS
// per-block then PLAIN coalesced partials store (no global atomics).
// No prefetch, no min-waves pin: target VGPR<=64 (8 waves/SIMD cliff).
// ---------------------------------------------------------------------------
__global__ __launch_bounds__(256) void k1_stats(
    const float* __restrict__ e1, const float* __restrict__ e2,
    const float* __restrict__ qW, const float* __restrict__ qb,
    const float* __restrict__ kW, const float* __restrict__ kb,
    const float* __restrict__ vW, const float* __restrict__ vb,
    char* __restrict__ ws) {

    const int tid = threadIdx.x;
    const int lane = tid & 63;
    const int widx = tid >> 6;
    const int col = lane & 15;      // n-index (e_lo / d) in MFMA layouts
    const int quad = lane >> 4;

    __shared__ __align__(16) unsigned short qk_lds[4][2][16 * 40]; // padded rows (80B)
    __shared__ float Dblk[256];
    Dblk[tid] = 0.f;
    __syncthreads();

    // Weight B-fragments: B_h[k=l][n=e_lo] = W[e_lo+16h][l], lane holds 8 consecutive l.
    s16x8 wq[2], wk[2], wv[2];
    f32x4 cbq[2], cbk[2], cbv[2];   // bias pre-loaded into MFMA accumulators
#pragma unroll
    for (int h = 0; h < 2; ++h) {
        int row = col + 16 * h;
        const float4* pq = (const float4*)(qW + row * 32 + quad * 8);
        const float4* pk = (const float4*)(kW + row * 32 + quad * 8);
        const float4* pv = (const float4*)(vW + row * 32 + quad * 8);
        wq[h] = cvt8(pq[0], pq[1]);
        wk[h] = cvt8(pk[0], pk[1]);
        wv[h] = cvt8(pv[0], pv[1]);
        float qv_ = qb[row], kv_ = kb[row], vv_ = vb[row];
        cbq[h] = (f32x4){qv_, qv_, qv_, qv_};
        cbk[h] = (f32x4){kv_, kv_, kv_, kv_};
        cbv[h] = (f32x4){vv_, vv_, vv_, vv_};
    }

    unsigned short* qbuf = qk_lds[widx][0];
    unsigned short* kbuf = qk_lds[widx][1];
    float dacc[4] = {0.f, 0.f, 0.f, 0.f};
    char* evbase = ws + WS_EV;
    const f32x4 z = {0.f, 0.f, 0.f, 0.f};

    const int gw = blockIdx.x * 4 + widx;
    for (int i = 0; i < 8; ++i) {
        const int b = gw * 8 + i;
        // A-fragments of X1, X2: lane holds X[c=col][l = quad*8 .. +7]
        const float4* x1p = (const float4*)(e1 + (size_t)b * 512 + col * 32 + quad * 8);
        const float4* x2p = (const float4*)(e2 + (size_t)b * 512 + col * 32 + quad * 8);
        float4 a0 = x1p[0], a1 = x1p[1];
        float4 b0 = x2p[0], b1 = x2p[1];
        s16x8 fx1 = cvt8(a0, a1);
        s16x8 fx2 = cvt8(b0, b1);

        // ---- Q: linears, product, LDS stage (transpose to A-frag layout) ----
        {
            f32x4 q1v[2], q2v[2];
#pragma unroll
            for (int h = 0; h < 2; ++h) {
                q1v[h] = MFMA(fx1, wq[h], cbq[h]);
                q2v[h] = MFMA(fx2, wq[h], cbq[h]);
            }
            // C/D layout: value (h,r) = M[row=quad*4+r][e=col+16h]; LDS rows
            // store permuted e' = e_lo*2 + h (perm shared by Q and K)
#pragma unroll
            for (int r = 0; r < 4; ++r) {
                int w = (quad * 4 + r) * 20 + col;   // uint index, row stride 20 words
                ((unsigned*)qbuf)[w] = pack2(q1v[0][r] * q2v[0][r],
                                             q1v[1][r] * q2v[1][r]);
            }
        }
        // ---- K: same ----
        {
            f32x4 k1v[2], k2v[2];
#pragma unroll
            for (int h = 0; h < 2; ++h) {
                k1v[h] = MFMA(fx1, wk[h], cbk[h]);
                k2v[h] = MFMA(fx2, wk[h], cbk[h]);
            }
#pragma unroll
            for (int r = 0; r < 4; ++r) {
                int w = (quad * 4 + r) * 20 + col;
                ((unsigned*)kbuf)[w] = pack2(k1v[0][r] * k2v[0][r],
                                             k1v[1][r] * k2v[1][r]);
            }
        }
        // ---- V: independent of the LDS round trip — fills its latency shadow
        char* bbase = evbase + (size_t)b * 1536;
        {
            f32x4 v1v[2], v2v[2];
#pragma unroll
            for (int h = 0; h < 2; ++h) {
                v1v[h] = MFMA(fx1, wv[h], cbv[h]);
                v2v[h] = MFMA(fx2, wv[h], cbv[h]);
            }
            // V stored blocked for k2 B-frags: block(h, e_lo=col, c-half quad>>1)
#pragma unroll
            for (int h = 0; h < 2; ++h) {
                uint2 vst;
                vst.x = pack2(v1v[h][0] * v2v[h][0], v1v[h][1] * v2v[h][1]);
                vst.y = pack2(v1v[h][2] * v2v[h][2], v1v[h][3] * v2v[h][3]);
                *(uint2*)(bbase + 512 + ((h * 16 + col) * 2 + (quad >> 1)) * 16 + (quad & 1) * 8) = vst;
            }
        }

        // ---- read back RAW Q as A-frag, K as B-frag; S-MFMA issues at once
        s16x8 aq  = *(const s16x8*)(qbuf + col * 40 + quad * 8);
        s16x8 bk8 = *(const s16x8*)(kbuf + col * 40 + quad * 8);
        f32x4 S = MFMA(aq, bk8, z);   // S_raw[c=quad*4+r][d=col]

        // ---- norms in parallel with the S-MFMA (deferred normalization)
        float ssq = 0.f, ssk = 0.f;
#pragma unroll
        for (int j = 0; j < 8; ++j) {
            float qf = bf2f((unsigned short)aq[j]);  ssq += qf * qf;
            float kf = bf2f((unsigned short)bk8[j]); ssk += kf * kf;
        }
        ssq += __shfl_xor(ssq, 16); ssq += __shfl_xor(ssq, 32);
        ssk += __shfl_xor(ssk, 16); ssk += __shfl_xor(ssk, 32);
        float invq = 1.f / fmaxf(sqrtf(ssq), 1e-12f);   // at lane: row c = col
        float invk = 1.f / fmaxf(sqrtf(ssk), 1e-12f);   // at lane: row d = col
        // transpose invq to row indexing (S rows are quad*4+r)
        float iq0 = __shfl(invq, quad * 4 + 0);
        float iq1 = __shfl(invq, quad * 4 + 1);
        float iq2 = __shfl(invq, quad * 4 + 2);
        float iq3 = __shfl(invq, quad * 4 + 3);

        float ex0 = __expf(S[0] * (iq0 * invk));
        float ex1 = __expf(S[1] * (iq1 * invk));
        float ex2 = __expf(S[2] * (iq2 * invk));
        float ex3 = __expf(S[3] * (iq3 * invk));
        dacc[0] += ex0; dacc[1] += ex1; dacc[2] += ex2; dacc[3] += ex3;
        // E stored [d][c] bf16: lane covers c = quad*4 .. +3 at row d=col
        uint2 est; est.x = pack2(ex0, ex1); est.y = pack2(ex2, ex3);
        *(uint2*)(bbase + col * 32 + quad * 8) = est;
    }
    // Denominator: regs -> block LDS (atomics, conflict-free) -> PLAIN coalesced store
#pragma unroll
    for (int r = 0; r < 4; ++r)
        atomicAdd(&Dblk[col * 16 + quad * 4 + r], dacc[r]);
    __syncthreads();
    ((float*)(ws + WS_PART))[blockIdx.x * 256 + tid] = Dblk[tid];
}

// ---------------------------------------------------------------------------
// k1b: (a) blocks 0..95 also build bf16 p1W permuted into k2's i' order;
// (b) every block j tree-reduces the 2048 per-block partials for denominator
// j and stores 1/D[j] at ws[0..1KB).
// ---------------------------------------------------------------------------
__global__ __launch_bounds__(256) void k1b_prep(const float* __restrict__ p1W,
                                                char* __restrict__ ws) {
    const int t = threadIdx.x;
    const int idx = blockIdx.x * 256 + t;        // 256*256 = 65536
    if (idx < 24576) {                           // 48*512 permute elements
        int jj   = idx & 7;
        int lane = (idx >> 3) & 63;
        int ktnt = idx >> 9;
        int kt = ktnt & 15, nt = ktnt >> 4;
        int n_lo = lane & 15, q8 = lane >> 4;
        int j2  = nt * 16 + n_lo;                // output neuron [0,48)
        int ip  = kt * 32 + q8 * 8 + jj;         // i' in [0,512)
        int e_lo = ip >> 5, qq = (ip >> 3) & 3, hh = (ip >> 2) & 1, r = ip & 3;
        int orig = (qq * 4 + r) * 32 + (e_lo + 16 * hh);
        ((unsigned short*)(ws + WS_P1W))[idx] = f2bf(p1W[j2 * 512 + orig]);
    }
    // Reduce partials[:, j] for j = blockIdx.x, store reciprocal
    const float* part = (const float*)(ws + WS_PART);
    const int j = blockIdx.x;
    float s = 0.f;
#pragma unroll
    for (int k = 0; k < 8; ++k)
        s += part[(size_t)(k * 256 + t) * 256 + j];
    __shared__ float red[256];
    red[t] = s;
    __syncthreads();
    for (int o = 128; o > 0; o >>= 1) {
        if (t < o) red[t] += red[t + o];
        __syncthreads();
    }
    if (t == 0) ((float*)ws)[j] = 1.f / red[0];
}

// ---------------------------------------------------------------------------
// k2: cooperative 4-wave block over ONE 16-batch group.  Phase1 (prefetched
// E/V loads): each wave computes 4 of the 16 per-batch out[d][e] rows into a
// shared 16KB H (bf16, XOR-swizzled chunks).  Phase2 (prefetched weights):
// each wave takes 4 of the 16 k-tiles of MLP1 (MFMA), partial accs reduced
// through LDS (aliased over H).  Phase3: ALL FOUR waves — wave w handles
// r = w — bias+relu, MLP2, normalize, store.  Tail constants hoisted; 1/D
// precomputed by k1b.
// ---------------------------------------------------------------------------
__global__ __launch_bounds__(256) void k2_apply(
    const char* __restrict__ ws, const float* __restrict__ p1b,
    const float* __restrict__ p2W, const float* __restrict__ p2b,
    float* __restrict__ out) {

    const int tid = threadIdx.x;
    const int lane = tid & 63;
    const int widx = tid >> 6;
    const int col = lane & 15;
    const int quad = lane >> 4;
    const int qm = quad & 1;        // mirrored address for upper quads

    __shared__ __align__(16) unsigned short Hs[16 * 512];   // 16 KiB
    float* P = (float*)Hs;          // aliased partial-sum buffer (12 KiB <= 16 KiB)

    // Hoisted tail constants — issued first, latency hidden under phases 1-2
    float p1bias[3], p2w[3][3];
#pragma unroll
    for (int nt = 0; nt < 3; ++nt) {
        p1bias[nt] = p1b[col + 16 * nt];
#pragma unroll
        for (int t2 = 0; t2 < 3; ++t2) p2w[nt][t2] = p2W[t2 * 48 + col + 16 * nt];
    }
    const float pb0 = p2b[0], pb1 = p2b[1], pb2 = p2b[2];

    // 1/denominator (precomputed by k1b), vector-loaded
    const float* Dws = (const float*)ws;
    const float4 dva = *(const float4*)(Dws + col * 16 + qm * 8);
    const float4 dvb = *(const float4*)(Dws + col * 16 + qm * 8 + 4);
    float dinv[8] = {dva.x, dva.y, dva.z, dva.w, dvb.x, dvb.y, dvb.z, dvb.w};

    const char* evbase = ws + WS_EV;
    const unsigned short* p1wp = (const unsigned short*)(ws + WS_P1W);
    const int g = blockIdx.x;
    const f32x4 z = {0.f, 0.f, 0.f, 0.f};
    const s16x8 zz = {0, 0, 0, 0, 0, 0, 0, 0};

    // Phase 1: out[d][e] for batches i = widx*4 .. +3 -> H rows (bf16, swizzled)
    {
        const char* bb0 = evbase + (size_t)(g * 16 + widx * 4) * 1536;
        const int eoff  = col * 32 + qm * 16;
        const int voff0 = 512 + (col * 2 + qm) * 16;
        const int voff1 = 512 + ((16 + col) * 2 + qm) * 16;
        s16x8 ne  = *(const s16x8*)(bb0 + eoff);
        s16x8 nv0 = *(const s16x8*)(bb0 + voff0);
        s16x8 nv1 = *(const s16x8*)(bb0 + voff1);
#pragma unroll
        for (int ii = 0; ii < 4; ++ii) {
            s16x8 eraw = ne, bf0 = nv0, bf1 = nv1;
            if (ii < 3) {
                const char* nb = bb0 + (size_t)(ii + 1) * 1536;
                ne  = *(const s16x8*)(nb + eoff);
                nv0 = *(const s16x8*)(nb + voff0);
                nv1 = *(const s16x8*)(nb + voff1);
            }
            float ef[8];
#pragma unroll
            for (int j = 0; j < 8; ++j)
                ef[j] = bf2f((unsigned short)eraw[j]) * dinv[j];
            uint4 ua;
            ua.x = pack2(ef[0], ef[1]); ua.y = pack2(ef[2], ef[3]);
            ua.z = pack2(ef[4], ef[5]); ua.w = pack2(ef[6], ef[7]);
            s16x8 afrag = __builtin_bit_cast(s16x8, ua);
            if (quad >= 2) { afrag = zz; bf0 = zz; bf1 = zz; }  // K-padding (c>=16 -> 0)
            f32x4 o0 = MFMA(afrag, bf0, z);   // out[d=quad*4+r][e=col]
            f32x4 o1 = MFMA(afrag, bf1, z);   // out[d=quad*4+r][e=col+16]
            uint4 uh;
            uh.x = pack2(o0[0], o0[1]); uh.y = pack2(o0[2], o0[3]);
            uh.z = pack2(o1[0], o1[1]); uh.w = pack2(o1[2], o1[3]);
            const int i = widx * 4 + ii;
            int chunk = (col * 4 + quad) ^ (i & 7);   // 16B-chunk XOR swizzle
            *(uint4*)(Hs + i * 512 + chunk * 8) = uh;
        }
    }
    __syncthreads();

    // Phase 2: MLP1 — H[16 x 512] @ p1Wp^T, wave widx handles kt = widx*4..+3
    f32x4 acc[3] = {z, z, z};
    {
        const int kt0 = widx * 4;
        s16x8 nw0 = *(const s16x8*)(p1wp + ((0 * 16 + kt0) * 64 + lane) * 8);
        s16x8 nw1 = *(const s16x8*)(p1wp + ((1 * 16 + kt0) * 64 + lane) * 8);
        s16x8 nw2 = *(const s16x8*)(p1wp + ((2 * 16 + kt0) * 64 + lane) * 8);
#pragma unroll
        for (int t2 = 0; t2 < 4; ++t2) {
            const int kt = widx * 4 + t2;
            s16x8 w0 = nw0, w1 = nw1, w2 = nw2;
            if (t2 < 3) {
                nw0 = *(const s16x8*)(p1wp + ((0 * 16 + kt + 1) * 64 + lane) * 8);
                nw1 = *(const s16x8*)(p1wp + ((1 * 16 + kt + 1) * 64 + lane) * 8);
                nw2 = *(const s16x8*)(p1wp + ((2 * 16 + kt + 1) * 64 + lane) * 8);
            }
            int chunk = (kt * 4 + quad) ^ (col & 7);
            s16x8 a = *(const s16x8*)(Hs + col * 512 + chunk * 8);
            acc[0] = MFMA(a, w0, acc[0]);
            acc[1] = MFMA(a, w1, acc[1]);
            acc[2] = MFMA(a, w2, acc[2]);
        }
    }
    __syncthreads();   // H reads done before P overwrites it

    // partials -> LDS: P[widx][lane][nt*4+r], lane stride 12 floats (48B)
#pragma unroll
    for (int nt = 0; nt < 3; ++nt)
        *(f32x4*)(P + (widx * 64 + lane) * 12 + nt * 4) = acc[nt];
    __syncthreads();

    // Phase 3: all 4 waves — wave widx handles r = widx (batches quad*4+widx)
    {
        float s3[3] = {0.f, 0.f, 0.f};
#pragma unroll
        for (int w = 0; w < 4; ++w)
#pragma unroll
            for (int nt = 0; nt < 3; ++nt)
                s3[nt] += P[(w * 64 + lane) * 12 + nt * 4 + widx];
        float pp[3] = {0.f, 0.f, 0.f};
#pragma unroll
        for (int nt = 0; nt < 3; ++nt) {
            float hv = fmaxf(s3[nt] + p1bias[nt], 0.f);
            pp[0] += hv * p2w[nt][0];
            pp[1] += hv * p2w[nt][1];
            pp[2] += hv * p2w[nt][2];
        }
#pragma unroll
        for (int m = 1; m <= 8; m <<= 1) {
            pp[0] += __shfl_xor(pp[0], m);
            pp[1] += __shfl_xor(pp[1], m);
            pp[2] += __shfl_xor(pp[2], m);
        }
        float h0 = pp[0] + pb0, h1 = pp[1] + pb1, h2 = pp[2] + pb2;
        float inv = 1.f / fmaxf(sqrtf(h0 * h0 + h1 * h1 + h2 * h2), 1e-12f);
        if (col < 3) {
            float v = (col == 0) ? h0 : ((col == 1) ? h1 : h2);
            out[(size_t)(g * 16 + quad * 4 + widx) * 3 + col] = v * inv;
        }
    }
}

// ---------------------------------------------------------------------------
extern "C" void kernel_launch(void* const* d_in, const int* in_sizes, int n_in,
                              void* d_out, int out_size, void* d_ws, size_t ws_size,
                              hipStream_t stream) {
    const float* e1  = (const float*)d_in[0];
    const float* e2  = (const float*)d_in[1];
    const float* qW  = (const float*)d_in[2];
    const float* qb  = (const float*)d_in[3];
    const float* kW  = (const float*)d_in[4];
    const float* kb  = (const float*)d_in[5];
    const float* vW  = (const float*)d_in[6];
    const float* vb  = (const float*)d_in[7];
    const float* p1W = (const float*)d_in[8];
    const float* p1b = (const float*)d_in[9];
    const float* p2W = (const float*)d_in[10];
    const float* p2b = (const float*)d_in[11];
    float* out = (float*)d_out;
    char* ws = (char*)d_ws;

    k1_stats<<<2048, 256, 0, stream>>>(e1, e2, qW, qb, kW, kb, vW, vb, ws);
    k1b_prep<<<256, 256, 0, stream>>>(p1W, ws);
    k2_apply<<<4096, 256, 0, stream>>>(ws, p1b, p2W, p2b, out);
}